// Round 4
// baseline (1323.270 us; speedup 1.0000x reference)
//
#include <hip/hip_runtime.h>
#include <hip/hip_bf16.h>
#include <math.h>

#define H 256
#define NIN 512
#define NHEADS 4
#define BM 64
#define LOG2E 1.4426950408889634f

typedef __attribute__((ext_vector_type(8))) short short8;
typedef __attribute__((ext_vector_type(4))) short short4v;
typedef __attribute__((ext_vector_type(4))) float floatx4;

__device__ __forceinline__ float4 ld4(const float* p){ return *reinterpret_cast<const float4*>(p); }

__device__ __forceinline__ short f2bf(float x){
    __hip_bfloat16 h = __float2bfloat16(x);
    return *reinterpret_cast<short*>(&h);
}
__device__ __forceinline__ float bf2f(short h){
    return __uint_as_float(((unsigned)(unsigned short)h) << 16);
}
__device__ __forceinline__ float fexp2(float x){ return __builtin_amdgcn_exp2f(x); }
__device__ __forceinline__ float frcp(float x){ return __builtin_amdgcn_rcpf(x); }

// tanh-form GELU with hw exp/rcp: max dev from exact ~1e-3
__device__ __forceinline__ float gelu_fast(float x){
    float y = x * fmaf(x*x, 0.0356774081f, 0.7978845608f);
    float t = fexp2(-2.8853900818f * fabsf(y));          // e^{-2|y|}
    float th = (1.f - t) * frcp(1.f + t);
    th = copysignf(th, y);
    return 0.5f * x * (1.f + th);
}
__device__ __forceinline__ floatx4 mfma16(short8 a, short8 b, floatx4 c){
    return __builtin_amdgcn_mfma_f32_16x16x32_bf16(a, b, c, 0, 0, 0);
}
__device__ __forceinline__ short8 pack8(float4 a, float4 b){
    short8 v;
    v[0]=f2bf(a.x); v[1]=f2bf(a.y); v[2]=f2bf(a.z); v[3]=f2bf(a.w);
    v[4]=f2bf(b.x); v[5]=f2bf(b.y); v[6]=f2bf(b.z); v[7]=f2bf(b.w);
    return v;
}

#define ZERO_ACC() do { \
    _Pragma("unroll") \
    for (int i_=0;i_<4;i_++){ \
        _Pragma("unroll") \
        for (int j_=0;j_<4;j_++) acc[i_][j_] = (floatx4){0.f,0.f,0.f,0.f}; \
    } \
} while(0)

// K=64 chunk: A fragments straight from global f32 rows arow[rb], B from WPTR
#define MFMA_CH_G(WPTR, KW, KOFF) do { \
    _Pragma("unroll") \
    for (int s_=0;s_<2;s_++){ \
        short8 bfr_[4]; \
        _Pragma("unroll") \
        for (int n_=0;n_<4;n_++) \
            bfr_[n_] = *reinterpret_cast<const short8*>( \
                &(WPTR)[(size_t)(c0 + n_*16 + lr)*(KW) + (KOFF) + s_*32 + lh*8]); \
        short8 af_[4]; \
        _Pragma("unroll") \
        for (int rb_=0;rb_<4;rb_++){ \
            const float* ap_ = arow[rb_] + (KOFF) + s_*32 + lh*8; \
            af_[rb_] = pack8(ld4(ap_), ld4(ap_ + 4)); \
        } \
        _Pragma("unroll") \
        for (int n_=0;n_<4;n_++) \
            _Pragma("unroll") \
            for (int rb_=0;rb_<4;rb_++) \
                acc[rb_][n_] = mfma16(af_[rb_], bfr_[n_], acc[rb_][n_]); \
    } \
} while(0)

// K=64 chunk: A from LDS xarena (stride 264 shorts), B from WPTR
#define MFMA_CH_L(AOFF, WPTR, KW, KOFF) do { \
    _Pragma("unroll") \
    for (int s_=0;s_<2;s_++){ \
        short8 bfr_[4]; \
        _Pragma("unroll") \
        for (int n_=0;n_<4;n_++) \
            bfr_[n_] = *reinterpret_cast<const short8*>( \
                &(WPTR)[(size_t)(c0 + n_*16 + lr)*(KW) + (KOFF) + s_*32 + lh*8]); \
        short8 af_[4]; \
        _Pragma("unroll") \
        for (int rb_=0;rb_<4;rb_++) \
            af_[rb_] = *reinterpret_cast<const short8*>( \
                &xarena[rb_*16+lr][(AOFF) + s_*32 + lh*8]); \
        _Pragma("unroll") \
        for (int n_=0;n_<4;n_++) \
            _Pragma("unroll") \
            for (int rb_=0;rb_<4;rb_++) \
                acc[rb_][n_] = mfma16(af_[rb_], bfr_[n_], acc[rb_][n_]); \
    } \
} while(0)

// ---------------- K0: per-node edge ranges (center_id sorted) ----------------
__global__ void k_ranges(const int* __restrict__ center, int* __restrict__ start, int E, int N)
{
    int n = blockIdx.x*blockDim.x + threadIdx.x;
    if (n > N) return;
    if (n == N){ start[N] = E; return; }
    int lo = 0, hi = E;
    while (lo < hi){ int mid = (lo+hi)>>1; if (center[mid] < n) lo = mid+1; else hi = mid; }
    start[n] = lo;
}

// ------------- weight convert+transpose: dst[c][k] = bf16(src[k][c]), src [K][256] -------------
__global__ void __launch_bounds__(256)
k_wconv(const float* __restrict__ src, short* __restrict__ dst, int K)
{
    __shared__ float t[32][33];
    const int k0 = blockIdx.x*32, c0 = blockIdx.y*32;
    const int tid = threadIdx.x;
    const int r = tid >> 3, q = tid & 7;
    float4 v = ld4(&src[(size_t)(k0 + r)*H + c0 + q*4]);
    t[r][q*4+0] = v.x; t[r][q*4+1] = v.y; t[r][q*4+2] = v.z; t[r][q*4+3] = v.w;
    __syncthreads();
    short4v o;
    o[0]=f2bf(t[q*4+0][r]); o[1]=f2bf(t[q*4+1][r]); o[2]=f2bf(t[q*4+2][r]); o[3]=f2bf(t[q*4+3][r]);
    *reinterpret_cast<short4v*>(&dst[(size_t)(c0 + r)*K + k0 + q*4]) = o;
}

// ------------- pad bias-W3 to [16][256] bf16 (cols 4..15 zero) -------------
__global__ void k_w3pad(const float* __restrict__ b3w, short* __restrict__ dst)
{
    const int k = threadIdx.x;
    #pragma unroll
    for (int c=0;c<16;c++)
        dst[c*H + k] = (c < NHEADS) ? f2bf(b3w[(size_t)k*NHEADS + c]) : (short)0;
}

// ------------- nodebias[n][j] = hV[n]@b1w[:256,j] + b1b[j]  (f32 VALU) -------------
__global__ void __launch_bounds__(256)
k_nodebias(const float* __restrict__ hV, const float* __restrict__ b1w,
           const float* __restrict__ b1b, float* __restrict__ nb, int N)
{
    __shared__ float ps[8][260];
    const int n0 = blockIdx.x*8;
    const int tid = threadIdx.x;
    {
        int r = tid >> 5, cq = (tid & 31)*8;
        *reinterpret_cast<float4*>(&ps[r][cq])   = ld4(&hV[(size_t)(n0+r)*H + cq]);
        *reinterpret_cast<float4*>(&ps[r][cq+4]) = ld4(&hV[(size_t)(n0+r)*H + cq + 4]);
    }
    __syncthreads();
    float a[8];
    float bias = b1b[tid];
    #pragma unroll
    for (int i=0;i<8;i++) a[i] = bias;
    #pragma unroll 4
    for (int k=0;k<H;k++){
        float w = b1w[(size_t)k*H + tid];
        #pragma unroll
        for (int i=0;i<8;i++) a[i] = fmaf(ps[i][k], w, a[i]);
    }
    #pragma unroll
    for (int i=0;i<8;i++) nb[(size_t)(n0+i)*H + tid] = a[i];
}

// ---------------- K1: bias MLP (bf16 MFMA, BM=64, no A-staging) -> logits ----------------
__global__ void __launch_bounds__(256,4)
k_bias2(const float* __restrict__ hE,
        const short* __restrict__ Wt1,      // [256][512]
        const short* __restrict__ Wt2,      // [256][256]
        const short* __restrict__ W3p,      // [16][256] padded
        const float* __restrict__ b3b,
        const float* __restrict__ b2b,
        const float* __restrict__ nodebias, // [N][256] (includes b1b)
        const int* __restrict__ center,
        float* __restrict__ logits, int E)
{
    __shared__ short xarena[BM][264];
    __shared__ int   csh[BM];

    const int tid = threadIdx.x;
    const int lane = tid & 63, w = tid >> 6;
    const int lr = lane & 15, lh = lane >> 4;
    const int e0 = blockIdx.x * BM;
    const int c0 = w * 64;

    if (tid < BM){ int ge = e0 + tid; csh[tid] = center[ge < E ? ge : E-1]; }

    const float* arow[4];
    #pragma unroll
    for (int rb=0;rb<4;rb++){
        int r = e0 + rb*16 + lr; if (r >= E) r = E-1;
        arow[rb] = hE + (size_t)r*NIN;
    }

    floatx4 acc[4][4];
    ZERO_ACC();

    // ---- layer1: K=512, barrier-free (A in-register from global)
    for (int ch = 0; ch < 8; ch++)
        MFMA_CH_G(Wt1, NIN, ch*64);
    __syncthreads();   // csh ready; xarena about to be written
    // epilogue1: + nodebias[center], ReLU -> xarena bf16
    #pragma unroll
    for (int rb=0;rb<4;rb++)
        #pragma unroll
        for (int j=0;j<4;j++){
            const int row = rb*16 + lh*4 + j;
            const float* nb = nodebias + (size_t)csh[row]*H + c0 + lr;
            #pragma unroll
            for (int n=0;n<4;n++)
                xarena[row][c0 + n*16 + lr] = f2bf(fmaxf(acc[rb][n][j] + nb[n*16], 0.f));
        }
    __syncthreads();

    // ---- layer2: K=256 (read all, then overwrite)
    ZERO_ACC();
    for (int ch = 0; ch < 4; ch++)
        MFMA_CH_L(ch*64, Wt2, H, ch*64);
    float bb[4];
    #pragma unroll
    for (int n=0;n<4;n++) bb[n] = b2b[c0 + n*16 + lr];
    __syncthreads();
    #pragma unroll
    for (int rb=0;rb<4;rb++)
        #pragma unroll
        for (int j=0;j<4;j++){
            const int row = rb*16 + lh*4 + j;
            #pragma unroll
            for (int n=0;n<4;n++)
                xarena[row][c0 + n*16 + lr] = f2bf(fmaxf(acc[rb][n][j] + bb[n], 0.f));
        }
    __syncthreads();

    // ---- layer3: K=256, 16 padded cols (4 heads); all waves compute, wave0 writes
    floatx4 a3[4];
    #pragma unroll
    for (int rb=0;rb<4;rb++) a3[rb] = (floatx4){0.f,0.f,0.f,0.f};
    for (int ch = 0; ch < 4; ch++){
        #pragma unroll
        for (int s=0;s<2;s++){
            short8 bfr = *reinterpret_cast<const short8*>(&W3p[lr*H + ch*64 + s*32 + lh*8]);
            #pragma unroll
            for (int rb=0;rb<4;rb++){
                short8 af = *reinterpret_cast<const short8*>(&xarena[rb*16+lr][ch*64 + s*32 + lh*8]);
                a3[rb] = mfma16(af, bfr, a3[rb]);
            }
        }
    }
    if (w == 0 && lr < NHEADS){
        float bias = b3b[lr];
        #pragma unroll
        for (int rb=0;rb<4;rb++)
            #pragma unroll
            for (int j=0;j<4;j++){
                int ge = e0 + rb*16 + lh*4 + j;
                if (ge < E) logits[(size_t)ge*NHEADS + lr] = (a3[rb][j] + bias) * 0.125f;
            }
    }
}

// ---------------- K2: per-node softmax stats ----------------
__global__ void k_smstats(const float* __restrict__ logits, const int* __restrict__ start,
                          float* __restrict__ mbuf, float* __restrict__ dbuf)
{
    int n = blockIdx.x;
    int s = start[n], e_end = start[n+1];
    int lane = threadIdx.x;
    int i = lane >> 2, hh = lane & 3;
    float mx = -INFINITY;
    for (int b = s + i; b < e_end; b += 16) mx = fmaxf(mx, logits[(size_t)b*NHEADS + hh]);
    #pragma unroll
    for (int off=4; off<64; off<<=1) mx = fmaxf(mx, __shfl_xor(mx, off, 64));
    float sum = 0.f;
    for (int b = s + i; b < e_end; b += 16) sum += expf(logits[(size_t)b*NHEADS + hh] - mx);
    #pragma unroll
    for (int off=4; off<64; off<<=1) sum += __shfl_xor(sum, off, 64);
    if (lane < 4){ mbuf[(size_t)n*NHEADS + hh] = mx; dbuf[(size_t)n*NHEADS + hh] = sum; }
}

// ---------------- K3: value MLP (bf16 MFMA, BM=64, no A-staging) + attend + scatter ----------------
__global__ void __launch_bounds__(256,4)
k_wv2(const float* __restrict__ hE,
      const short* __restrict__ Wt1, const float* __restrict__ b1v,
      const short* __restrict__ Wt2, const float* __restrict__ b2v,
      const short* __restrict__ Wt3, const float* __restrict__ b3v,
      const int* __restrict__ center, const float* __restrict__ logits,
      const float* __restrict__ mbuf, const float* __restrict__ dbuf,
      float* __restrict__ pre, int E)
{
    __shared__ short xarena[BM][264];
    __shared__ int   csh[BM];

    const int tid = threadIdx.x;
    const int lane = tid & 63, w = tid >> 6;
    const int lr = lane & 15, lh = lane >> 4;
    const int e0 = blockIdx.x * BM;
    const int c0 = w * 64;

    if (tid < BM){ int ge = e0 + tid; csh[tid] = center[ge < E ? ge : E-1]; }

    const float* arow[4];
    #pragma unroll
    for (int rb=0;rb<4;rb++){
        int r = e0 + rb*16 + lr; if (r >= E) r = E-1;
        arow[rb] = hE + (size_t)r*NIN;
    }

    floatx4 acc[4][4];
    ZERO_ACC();

    // ---- layer1: K=512, barrier-free
    for (int ch = 0; ch < 8; ch++)
        MFMA_CH_G(Wt1, NIN, ch*64);
    __syncthreads();   // xarena about to be written
    {
        float bc[4];
        #pragma unroll
        for (int n=0;n<4;n++) bc[n] = b1v[c0 + n*16 + lr];
        #pragma unroll
        for (int rb=0;rb<4;rb++)
            #pragma unroll
            for (int j=0;j<4;j++){
                const int row = rb*16 + lh*4 + j;
                #pragma unroll
                for (int n=0;n<4;n++)
                    xarena[row][c0 + n*16 + lr] = f2bf(gelu_fast(acc[rb][n][j] + bc[n]));
            }
    }
    __syncthreads();

    // ---- layer2: K=256
    ZERO_ACC();
    for (int ch = 0; ch < 4; ch++)
        MFMA_CH_L(ch*64, Wt2, H, ch*64);
    float bc2[4];
    #pragma unroll
    for (int n=0;n<4;n++) bc2[n] = b2v[c0 + n*16 + lr];
    __syncthreads();
    #pragma unroll
    for (int rb=0;rb<4;rb++)
        #pragma unroll
        for (int j=0;j<4;j++){
            const int row = rb*16 + lh*4 + j;
            #pragma unroll
            for (int n=0;n<4;n++)
                xarena[row][c0 + n*16 + lr] = f2bf(gelu_fast(acc[rb][n][j] + bc2[n]));
        }
    __syncthreads();

    // ---- layer3: K=256 (no activation)
    ZERO_ACC();
    for (int ch = 0; ch < 4; ch++)
        MFMA_CH_L(ch*64, Wt3, H, ch*64);
    float bc3[4];
    #pragma unroll
    for (int n=0;n<4;n++) bc3[n] = b3v[c0 + n*16 + lr];
    __syncthreads();   // all xarena reads done

    // ---- epilogue: attend (head == wave), store scaled bf16, segmented column reduce
    #pragma unroll
    for (int rb=0;rb<4;rb++)
        #pragma unroll
        for (int j=0;j<4;j++){
            const int row = rb*16 + lh*4 + j;
            const int ge = e0 + row;
            float att = 0.f;
            if (ge < E){
                const int c = csh[row];
                att = fexp2((logits[(size_t)ge*NHEADS + w] - mbuf[(size_t)c*NHEADS + w]) * LOG2E)
                      * frcp(dbuf[(size_t)c*NHEADS + w]);
            }
            #pragma unroll
            for (int n=0;n<4;n++)
                xarena[row][c0 + n*16 + lr] = f2bf((acc[rb][n][j] + bc3[n]) * att);
        }
    __syncthreads();
    {
        const int col = tid;
        float s = 0.f; int cur = csh[0];
        for (int e=0;e<BM;e++){
            int c = csh[e];
            if (c != cur){ atomicAdd(&pre[(size_t)cur*H + col], s); s = 0.f; cur = c; }
            s += bf2f(xarena[e][col]);
        }
        atomicAdd(&pre[(size_t)cur*H + col], s);
    }
}

// ---------------- K4: out = pre @ wo (f32) ----------------
__global__ void __launch_bounds__(256)
k_out(const float* __restrict__ pre, const float* __restrict__ wo,
      float* __restrict__ out, int N)
{
    __shared__ float ps[8][260];
    const int tid = threadIdx.x;
    const int nb = blockIdx.x * 8;
    {
        int r = tid >> 5, c = (tid & 31) * 8;
        *reinterpret_cast<float4*>(&ps[r][c])   = ld4(&pre[(size_t)(nb+r)*H + c]);
        *reinterpret_cast<float4*>(&ps[r][c+4]) = ld4(&pre[(size_t)(nb+r)*H + c+4]);
    }
    __syncthreads();
    float a[8];
    #pragma unroll
    for (int i=0;i<8;i++) a[i]=0.f;
    #pragma unroll 4
    for (int k=0;k<H;k++){
        float w = wo[(size_t)k*H + tid];
        #pragma unroll
        for (int i=0;i<8;i++) a[i] = fmaf(ps[i][k], w, a[i]);
    }
    #pragma unroll
    for (int i=0;i<8;i++)
        out[(size_t)(nb+i)*H + tid] = a[i];
}

extern "C" void kernel_launch(void* const* d_in, const int* in_sizes, int n_in,
                              void* d_out, int out_size, void* d_ws, size_t ws_size,
                              hipStream_t stream)
{
    const float* hV   = (const float*)d_in[0];
    const float* hE   = (const float*)d_in[1];
    const float* wv1w = (const float*)d_in[2];
    const float* wv1b = (const float*)d_in[3];
    const float* wv2w = (const float*)d_in[4];
    const float* wv2b = (const float*)d_in[5];
    const float* wv3w = (const float*)d_in[6];
    const float* wv3b = (const float*)d_in[7];
    const float* b1w  = (const float*)d_in[8];
    const float* b1b  = (const float*)d_in[9];
    const float* b2w  = (const float*)d_in[10];
    const float* b2b  = (const float*)d_in[11];
    const float* b3w  = (const float*)d_in[12];
    const float* b3b  = (const float*)d_in[13];
    const float* wow  = (const float*)d_in[14];
    const int*   center = (const int*)d_in[15];

    const int E = in_sizes[15];
    const int N = in_sizes[0] / H;
    const int nblk = (E + BM - 1) / BM;

    float* pre      = (float*)d_ws;                       // N*H
    float* logits   = pre + (size_t)N*H;                  // E*4
    float* mbuf     = logits + (size_t)E*NHEADS;          // N*4
    float* dbuf     = mbuf + (size_t)N*NHEADS;            // N*4
    int*   start    = (int*)(dbuf + (size_t)N*NHEADS);    // N+1 (padded)
    float* nodebias = (float*)(start + ((N+1+3)&~3));     // N*H
    short* wt1b     = (short*)(nodebias + (size_t)N*H);   // 256*512
    short* wt2b     = wt1b + 256*512;                     // 256*256
    short* w3pb     = wt2b + 256*256;                     // 16*256
    short* wt1v     = w3pb + 16*256;                      // 256*512
    short* wt2v     = wt1v + 256*512;                     // 256*256
    short* wt3v     = wt2v + 256*256;                     // 256*256

    hipMemsetAsync(pre, 0, (size_t)N*H*sizeof(float), stream);
    k_ranges<<<(N+1+255)/256, 256, 0, stream>>>(center, start, E, N);
    k_wconv<<<dim3(16,8), 256, 0, stream>>>(b1w + 256*H, wt1b, 512);
    k_wconv<<<dim3(8,8),  256, 0, stream>>>(b2w,  wt2b, 256);
    k_w3pad<<<1, 256, 0, stream>>>(b3w, w3pb);
    k_wconv<<<dim3(16,8), 256, 0, stream>>>(wv1w, wt1v, 512);
    k_wconv<<<dim3(8,8),  256, 0, stream>>>(wv2w, wt2v, 256);
    k_wconv<<<dim3(8,8),  256, 0, stream>>>(wv3w, wt3v, 256);
    k_nodebias<<<N/8, 256, 0, stream>>>(hV, b1w, b1b, nodebias, N);
    k_bias2<<<nblk, 256, 0, stream>>>(hE, wt1b, wt2b, w3pb, b3b, b2b, nodebias, center, logits, E);
    k_smstats<<<N, 64, 0, stream>>>(logits, start, mbuf, dbuf);
    k_wv2<<<nblk, 256, 0, stream>>>(hE, wt1v, wv1b, wt2v, wv2b, wt3v, wv3b,
                                    center, logits, mbuf, dbuf, pre, E);
    k_out<<<N/8, 256, 0, stream>>>(pre, wow, (float*)d_out, N);
}

// Round 5
// 638.759 us; speedup vs baseline: 2.0716x; 2.0716x over previous
//
#include <hip/hip_runtime.h>
#include <hip/hip_bf16.h>
#include <math.h>

#define H 256
#define NIN 512
#define NHEADS 4
#define BM 64
#define LOG2E 1.4426950408889634f

typedef __attribute__((ext_vector_type(8))) short short8;
typedef __attribute__((ext_vector_type(4))) short short4v;
typedef __attribute__((ext_vector_type(4))) float floatx4;

__device__ __forceinline__ float4 ld4(const float* p){ return *reinterpret_cast<const float4*>(p); }

__device__ __forceinline__ short f2bf(float x){
    __hip_bfloat16 h = __float2bfloat16(x);
    return *reinterpret_cast<short*>(&h);
}
__device__ __forceinline__ float bf2f(short h){
    return __uint_as_float(((unsigned)(unsigned short)h) << 16);
}
__device__ __forceinline__ float fexp2(float x){ return __builtin_amdgcn_exp2f(x); }
__device__ __forceinline__ float frcp(float x){ return __builtin_amdgcn_rcpf(x); }

// tanh-form GELU with hw exp/rcp: max dev from exact ~1e-3
__device__ __forceinline__ float gelu_fast(float x){
    float y = x * fmaf(x*x, 0.0356774081f, 0.7978845608f);
    float t = fexp2(-2.8853900818f * fabsf(y));          // e^{-2|y|}
    float th = (1.f - t) * frcp(1.f + t);
    th = copysignf(th, y);
    return 0.5f * x * (1.f + th);
}
__device__ __forceinline__ floatx4 mfma16(short8 a, short8 b, floatx4 c){
    return __builtin_amdgcn_mfma_f32_16x16x32_bf16(a, b, c, 0, 0, 0);
}
__device__ __forceinline__ short8 pack8(float4 a, float4 b){
    short8 v;
    v[0]=f2bf(a.x); v[1]=f2bf(a.y); v[2]=f2bf(a.z); v[3]=f2bf(a.w);
    v[4]=f2bf(b.x); v[5]=f2bf(b.y); v[6]=f2bf(b.z); v[7]=f2bf(b.w);
    return v;
}

#define ZERO_ACC() do { \
    _Pragma("unroll") \
    for (int i_=0;i_<4;i_++){ \
        _Pragma("unroll") \
        for (int j_=0;j_<4;j_++) acc[i_][j_] = (floatx4){0.f,0.f,0.f,0.f}; \
    } \
} while(0)

// Load 8 B-fragments of one K=64 chunk from frag-major weight buffer.
// Frag-major layout: offset = (((cb*NCH + ch)*2 + s) << 9) + lane*8, cb = w*4 + n
#define LOADB(DST, WF, NCH, CH) do { \
    _Pragma("unroll") \
    for (int s_=0;s_<2;s_++) \
        _Pragma("unroll") \
        for (int n_=0;n_<4;n_++) \
            DST[s_][n_] = *reinterpret_cast<const short8*>( \
                &(WF)[(size_t)((((w*4+n_)*(NCH) + (CH))*2 + s_) << 9) + lane*8]); \
} while(0)

#define COPYB(DST, SRC) do { \
    _Pragma("unroll") \
    for (int s_=0;s_<2;s_++) \
        _Pragma("unroll") \
        for (int n_=0;n_<4;n_++) DST[s_][n_] = SRC[s_][n_]; \
} while(0)

// K=64 chunk MFMA: preloaded B frags BC, A from LDS (ABASE, stride ASTR shorts)
#define MFMA_LDS(BC, ABASE, ASTR) do { \
    _Pragma("unroll") \
    for (int s_=0;s_<2;s_++){ \
        short8 af_[4]; \
        _Pragma("unroll") \
        for (int rb_=0;rb_<4;rb_++) \
            af_[rb_] = *reinterpret_cast<const short8*>( \
                &(ABASE)[(rb_*16+lr)*(ASTR) + s_*32 + lh*8]); \
        _Pragma("unroll") \
        for (int n_=0;n_<4;n_++) \
            _Pragma("unroll") \
            for (int rb_=0;rb_<4;rb_++) \
                acc[rb_][n_] = mfma16(af_[rb_], BC[s_][n_], acc[rb_][n_]); \
    } \
} while(0)

// ---------------- K0: per-node edge ranges (center_id sorted) ----------------
__global__ void k_ranges(const int* __restrict__ center, int* __restrict__ start, int E, int N)
{
    int n = blockIdx.x*blockDim.x + threadIdx.x;
    if (n > N) return;
    if (n == N){ start[N] = E; return; }
    int lo = 0, hi = E;
    while (lo < hi){ int mid = (lo+hi)>>1; if (center[mid] < n) lo = mid+1; else hi = mid; }
    start[n] = lo;
}

// ------------- weight convert to frag-major bf16: src f32 [KK][256] -------------
// out[(((cb*NCH+ch)*2+s)<<9) + lane*8 + j] = bf16(src[(ch*64+s*32+(lane>>4)*8+j)][cb*16+(lane&15)])
__global__ void __launch_bounds__(256)
k_wconvf(const float* __restrict__ src, short* __restrict__ dst, int KK)
{
    const int cb = blockIdx.x;          // 0..15
    const int ch = blockIdx.y;          // 0..KK/64-1
    const int NCH = KK >> 6;
    const int t = threadIdx.x;
    const int s = t >> 7;
    const int rem = t & 127;
    const int ln = rem >> 1;
    const int j0 = (rem & 1) * 4;
    const int k = ch*64 + s*32 + ((ln>>4)<<3) + j0;
    const int col = cb*16 + (ln & 15);
    short4v o;
    o[0] = f2bf(src[(size_t)(k+0)*H + col]);
    o[1] = f2bf(src[(size_t)(k+1)*H + col]);
    o[2] = f2bf(src[(size_t)(k+2)*H + col]);
    o[3] = f2bf(src[(size_t)(k+3)*H + col]);
    *reinterpret_cast<short4v*>(&dst[(size_t)(((cb*NCH + ch)*2 + s) << 9) + ln*8 + j0]) = o;
}

// ------------- bias-W3 [256][4] -> frag-major padded 16 cols -------------
__global__ void k_w3padf(const float* __restrict__ b3w, short* __restrict__ dst)
{
    const int t = threadIdx.x;          // 256
    const int ch = t >> 6, ln = t & 63;
    const int col = ln & 15;
    #pragma unroll
    for (int s=0;s<2;s++){
        #pragma unroll
        for (int j=0;j<8;j++){
            int k = ch*64 + s*32 + ((ln>>4)<<3) + j;
            dst[((ch*2 + s) << 9) + ln*8 + j] =
                (col < NHEADS) ? f2bf(b3w[(size_t)k*NHEADS + col]) : (short)0;
        }
    }
}

// ------------- nodebias[n][j] = hV[n]@b1w[:256,j] + b1b[j]  (f32 VALU) -------------
__global__ void __launch_bounds__(256)
k_nodebias(const float* __restrict__ hV, const float* __restrict__ b1w,
           const float* __restrict__ b1b, float* __restrict__ nb, int N)
{
    __shared__ float ps[8][260];
    const int n0 = blockIdx.x*8;
    const int tid = threadIdx.x;
    {
        int r = tid >> 5, cq = (tid & 31)*8;
        *reinterpret_cast<float4*>(&ps[r][cq])   = ld4(&hV[(size_t)(n0+r)*H + cq]);
        *reinterpret_cast<float4*>(&ps[r][cq+4]) = ld4(&hV[(size_t)(n0+r)*H + cq + 4]);
    }
    __syncthreads();
    float a[8];
    float bias = b1b[tid];
    #pragma unroll
    for (int i=0;i<8;i++) a[i] = bias;
    #pragma unroll 4
    for (int k=0;k<H;k++){
        float w = b1w[(size_t)k*H + tid];
        #pragma unroll
        for (int i=0;i<8;i++) a[i] = fmaf(ps[i][k], w, a[i]);
    }
    #pragma unroll
    for (int i=0;i<8;i++) nb[(size_t)(n0+i)*H + tid] = a[i];
}

// ---------------- K1: bias MLP (bf16 MFMA, BM=64, B-pipelined) -> logits ----------------
__global__ void __launch_bounds__(256,3)
k_bias2(const float* __restrict__ hE,
        const short* __restrict__ Wf1,      // frag-major, NCH=8
        const short* __restrict__ Wf2,      // frag-major, NCH=4
        const short* __restrict__ W3f,      // frag-major padded, NCH=4, cb=0
        const float* __restrict__ b3b,
        const float* __restrict__ b2b,
        const float* __restrict__ nodebias, // [N][256] (includes b1b)
        const int* __restrict__ center,
        float* __restrict__ logits, int E)
{
    __shared__ short Alds[2][BM][72];
    __shared__ short xarena[BM][264];
    __shared__ int   csh[BM];

    const int tid = threadIdx.x;
    const int lane = tid & 63, w = tid >> 6;
    const int lr = lane & 15, lh = lane >> 4;
    const int e0 = blockIdx.x * BM;
    const int srow = tid >> 2, skq = tid & 3;
    const int gsrow = (e0 + srow < E) ? (e0 + srow) : (E-1);
    const float* aSrc = hE + (size_t)gsrow * NIN + skq * 16;

    if (tid < BM){ int ge = e0 + tid; csh[tid] = center[ge < E ? ge : E-1]; }

    floatx4 acc[4][4];
    ZERO_ACC();

    short8 bc[2][4], bn[2][4];
    LOADB(bc, Wf1, 8, 0);
    float4 pf[4];
    #pragma unroll
    for (int q=0;q<4;q++) pf[q] = ld4(aSrc + q*4);
    *reinterpret_cast<short8*>(&Alds[0][srow][skq*16])   = pack8(pf[0], pf[1]);
    *reinterpret_cast<short8*>(&Alds[0][srow][skq*16+8]) = pack8(pf[2], pf[3]);
    __syncthreads();

    // ---- layer1: K=512, double-buffered A, B prefetched one chunk ahead
    #pragma unroll
    for (int ch = 0; ch < 8; ch++){
        if (ch < 7){
            LOADB(bn, Wf1, 8, ch+1);
            #pragma unroll
            for (int q=0;q<4;q++) pf[q] = ld4(aSrc + (ch+1)*64 + q*4);
        }
        __builtin_amdgcn_s_setprio(1);
        MFMA_LDS(bc, &Alds[ch&1][0][0], 72);
        __builtin_amdgcn_s_setprio(0);
        if (ch < 7){
            *reinterpret_cast<short8*>(&Alds[(ch&1)^1][srow][skq*16])   = pack8(pf[0], pf[1]);
            *reinterpret_cast<short8*>(&Alds[(ch&1)^1][srow][skq*16+8]) = pack8(pf[2], pf[3]);
            COPYB(bc, bn);
        }
        __syncthreads();
    }
    const int c0 = w * 64;
    // epilogue1: + nodebias[center], ReLU -> xarena bf16
    #pragma unroll
    for (int rb=0;rb<4;rb++)
        #pragma unroll
        for (int j=0;j<4;j++){
            const int row = rb*16 + lh*4 + j;
            const float* nb = nodebias + (size_t)csh[row]*H + c0 + lr;
            #pragma unroll
            for (int n=0;n<4;n++)
                xarena[row][c0 + n*16 + lr] = f2bf(fmaxf(acc[rb][n][j] + nb[n*16], 0.f));
        }
    __syncthreads();

    // ---- layer2: K=256, A = xarena (read all, then overwrite)
    ZERO_ACC();
    LOADB(bc, Wf2, 4, 0);
    #pragma unroll
    for (int ch = 0; ch < 4; ch++){
        if (ch < 3) LOADB(bn, Wf2, 4, ch+1);
        __builtin_amdgcn_s_setprio(1);
        MFMA_LDS(bc, &xarena[0][ch*64], 264);
        __builtin_amdgcn_s_setprio(0);
        if (ch < 3) COPYB(bc, bn);
    }
    float bb[4];
    #pragma unroll
    for (int n=0;n<4;n++) bb[n] = b2b[c0 + n*16 + lr];
    __syncthreads();
    #pragma unroll
    for (int rb=0;rb<4;rb++)
        #pragma unroll
        for (int j=0;j<4;j++){
            const int row = rb*16 + lh*4 + j;
            #pragma unroll
            for (int n=0;n<4;n++)
                xarena[row][c0 + n*16 + lr] = f2bf(fmaxf(acc[rb][n][j] + bb[n], 0.f));
        }
    __syncthreads();

    // ---- layer3: K=256, 16 padded cols (4 heads); all waves compute, wave0 writes
    floatx4 a3[4];
    #pragma unroll
    for (int rb=0;rb<4;rb++) a3[rb] = (floatx4){0.f,0.f,0.f,0.f};
    short8 b3fr[4][2];
    #pragma unroll
    for (int ch=0;ch<4;ch++)
        #pragma unroll
        for (int s=0;s<2;s++)
            b3fr[ch][s] = *reinterpret_cast<const short8*>(&W3f[((ch*2+s)<<9) + lane*8]);
    #pragma unroll
    for (int ch=0;ch<4;ch++)
        #pragma unroll
        for (int s=0;s<2;s++)
            #pragma unroll
            for (int rb=0;rb<4;rb++){
                short8 af = *reinterpret_cast<const short8*>(&xarena[rb*16+lr][ch*64 + s*32 + lh*8]);
                a3[rb] = mfma16(af, b3fr[ch][s], a3[rb]);
            }
    if (w == 0 && lr < NHEADS){
        float bias = b3b[lr];
        #pragma unroll
        for (int rb=0;rb<4;rb++)
            #pragma unroll
            for (int j=0;j<4;j++){
                int ge = e0 + rb*16 + lh*4 + j;
                if (ge < E) logits[(size_t)ge*NHEADS + lr] = (a3[rb][j] + bias) * 0.125f;
            }
    }
}

// ---------------- K2: per-node softmax stats ----------------
__global__ void k_smstats(const float* __restrict__ logits, const int* __restrict__ start,
                          float* __restrict__ mbuf, float* __restrict__ dbuf)
{
    int n = blockIdx.x;
    int s = start[n], e_end = start[n+1];
    int lane = threadIdx.x;
    int i = lane >> 2, hh = lane & 3;
    float mx = -INFINITY;
    for (int b = s + i; b < e_end; b += 16) mx = fmaxf(mx, logits[(size_t)b*NHEADS + hh]);
    #pragma unroll
    for (int off=4; off<64; off<<=1) mx = fmaxf(mx, __shfl_xor(mx, off, 64));
    float sum = 0.f;
    for (int b = s + i; b < e_end; b += 16) sum += expf(logits[(size_t)b*NHEADS + hh] - mx);
    #pragma unroll
    for (int off=4; off<64; off<<=1) sum += __shfl_xor(sum, off, 64);
    if (lane < 4){ mbuf[(size_t)n*NHEADS + hh] = mx; dbuf[(size_t)n*NHEADS + hh] = sum; }
}

// ---------------- K3: value MLP (bf16 MFMA, BM=64, B-pipelined) + attend + scatter ----------------
__global__ void __launch_bounds__(256,3)
k_wv2(const float* __restrict__ hE,
      const short* __restrict__ Wf1, const float* __restrict__ b1v,
      const short* __restrict__ Wf2, const float* __restrict__ b2v,
      const short* __restrict__ Wf3, const float* __restrict__ b3v,
      const int* __restrict__ center, const float* __restrict__ logits,
      const float* __restrict__ mbuf, const float* __restrict__ dbuf,
      float* __restrict__ pre, int E)
{
    __shared__ short Alds[2][BM][72];
    __shared__ short xarena[BM][264];
    __shared__ int   csh[BM];

    const int tid = threadIdx.x;
    const int lane = tid & 63, w = tid >> 6;
    const int lr = lane & 15, lh = lane >> 4;
    const int e0 = blockIdx.x * BM;
    const int srow = tid >> 2, skq = tid & 3;
    const int gsrow = (e0 + srow < E) ? (e0 + srow) : (E-1);
    const float* aSrc = hE + (size_t)gsrow * NIN + skq * 16;

    if (tid < BM){ int ge = e0 + tid; csh[tid] = center[ge < E ? ge : E-1]; }

    floatx4 acc[4][4];
    ZERO_ACC();

    short8 bc[2][4], bn[2][4];
    LOADB(bc, Wf1, 8, 0);
    float4 pf[4];
    #pragma unroll
    for (int q=0;q<4;q++) pf[q] = ld4(aSrc + q*4);
    *reinterpret_cast<short8*>(&Alds[0][srow][skq*16])   = pack8(pf[0], pf[1]);
    *reinterpret_cast<short8*>(&Alds[0][srow][skq*16+8]) = pack8(pf[2], pf[3]);
    __syncthreads();

    // ---- layer1: K=512
    #pragma unroll
    for (int ch = 0; ch < 8; ch++){
        if (ch < 7){
            LOADB(bn, Wf1, 8, ch+1);
            #pragma unroll
            for (int q=0;q<4;q++) pf[q] = ld4(aSrc + (ch+1)*64 + q*4);
        }
        __builtin_amdgcn_s_setprio(1);
        MFMA_LDS(bc, &Alds[ch&1][0][0], 72);
        __builtin_amdgcn_s_setprio(0);
        if (ch < 7){
            *reinterpret_cast<short8*>(&Alds[(ch&1)^1][srow][skq*16])   = pack8(pf[0], pf[1]);
            *reinterpret_cast<short8*>(&Alds[(ch&1)^1][srow][skq*16+8]) = pack8(pf[2], pf[3]);
            COPYB(bc, bn);
        }
        __syncthreads();
    }
    const int c0 = w * 64;
    {
        float bcv[4];
        #pragma unroll
        for (int n=0;n<4;n++) bcv[n] = b1v[c0 + n*16 + lr];
        #pragma unroll
        for (int rb=0;rb<4;rb++)
            #pragma unroll
            for (int j=0;j<4;j++){
                const int row = rb*16 + lh*4 + j;
                #pragma unroll
                for (int n=0;n<4;n++)
                    xarena[row][c0 + n*16 + lr] = f2bf(gelu_fast(acc[rb][n][j] + bcv[n]));
            }
    }
    __syncthreads();

    // ---- layer2: K=256
    ZERO_ACC();
    LOADB(bc, Wf2, 4, 0);
    #pragma unroll
    for (int ch = 0; ch < 4; ch++){
        if (ch < 3) LOADB(bn, Wf2, 4, ch+1);
        __builtin_amdgcn_s_setprio(1);
        MFMA_LDS(bc, &xarena[0][ch*64], 264);
        __builtin_amdgcn_s_setprio(0);
        if (ch < 3) COPYB(bc, bn);
    }
    float bc2[4];
    #pragma unroll
    for (int n=0;n<4;n++) bc2[n] = b2v[c0 + n*16 + lr];
    __syncthreads();
    #pragma unroll
    for (int rb=0;rb<4;rb++)
        #pragma unroll
        for (int j=0;j<4;j++){
            const int row = rb*16 + lh*4 + j;
            #pragma unroll
            for (int n=0;n<4;n++)
                xarena[row][c0 + n*16 + lr] = f2bf(gelu_fast(acc[rb][n][j] + bc2[n]));
        }
    __syncthreads();

    // ---- layer3: K=256 (no activation)
    ZERO_ACC();
    LOADB(bc, Wf3, 4, 0);
    #pragma unroll
    for (int ch = 0; ch < 4; ch++){
        if (ch < 3) LOADB(bn, Wf3, 4, ch+1);
        __builtin_amdgcn_s_setprio(1);
        MFMA_LDS(bc, &xarena[0][ch*64], 264);
        __builtin_amdgcn_s_setprio(0);
        if (ch < 3) COPYB(bc, bn);
    }
    float bc3[4];
    #pragma unroll
    for (int n=0;n<4;n++) bc3[n] = b3v[c0 + n*16 + lr];
    __syncthreads();   // all xarena reads done

    // ---- epilogue: attend (head == wave), store scaled bf16, segmented column reduce
    #pragma unroll
    for (int rb=0;rb<4;rb++)
        #pragma unroll
        for (int j=0;j<4;j++){
            const int row = rb*16 + lh*4 + j;
            const int ge = e0 + row;
            float att = 0.f;
            if (ge < E){
                const int c = csh[row];
                att = fexp2((logits[(size_t)ge*NHEADS + w] - mbuf[(size_t)c*NHEADS + w]) * LOG2E)
                      * frcp(dbuf[(size_t)c*NHEADS + w]);
            }
            #pragma unroll
            for (int n=0;n<4;n++)
                xarena[row][c0 + n*16 + lr] = f2bf((acc[rb][n][j] + bc3[n]) * att);
        }
    __syncthreads();
    {
        const int col = tid;
        float s = 0.f; int cur = csh[0];
        for (int e=0;e<BM;e++){
            int c = csh[e];
            if (c != cur){ atomicAdd(&pre[(size_t)cur*H + col], s); s = 0.f; cur = c; }
            s += bf2f(xarena[e][col]);
        }
        atomicAdd(&pre[(size_t)cur*H + col], s);
    }
}

// ---------------- K4: out = pre @ wo (f32) ----------------
__global__ void __launch_bounds__(256)
k_out(const float* __restrict__ pre, const float* __restrict__ wo,
      float* __restrict__ out, int N)
{
    __shared__ float ps[8][260];
    const int tid = threadIdx.x;
    const int nb = blockIdx.x * 8;
    {
        int r = tid >> 5, c = (tid & 31) * 8;
        *reinterpret_cast<float4*>(&ps[r][c])   = ld4(&pre[(size_t)(nb+r)*H + c]);
        *reinterpret_cast<float4*>(&ps[r][c+4]) = ld4(&pre[(size_t)(nb+r)*H + c+4]);
    }
    __syncthreads();
    float a[8];
    #pragma unroll
    for (int i=0;i<8;i++) a[i]=0.f;
    #pragma unroll 4
    for (int k=0;k<H;k++){
        float w = wo[(size_t)k*H + tid];
        #pragma unroll
        for (int i=0;i<8;i++) a[i] = fmaf(ps[i][k], w, a[i]);
    }
    #pragma unroll
    for (int i=0;i<8;i++)
        out[(size_t)(nb+i)*H + tid] = a[i];
}

extern "C" void kernel_launch(void* const* d_in, const int* in_sizes, int n_in,
                              void* d_out, int out_size, void* d_ws, size_t ws_size,
                              hipStream_t stream)
{
    const float* hV   = (const float*)d_in[0];
    const float* hE   = (const float*)d_in[1];
    const float* wv1w = (const float*)d_in[2];
    const float* wv1b = (const float*)d_in[3];
    const float* wv2w = (const float*)d_in[4];
    const float* wv2b = (const float*)d_in[5];
    const float* wv3w = (const float*)d_in[6];
    const float* wv3b = (const float*)d_in[7];
    const float* b1w  = (const float*)d_in[8];
    const float* b1b  = (const float*)d_in[9];
    const float* b2w  = (const float*)d_in[10];
    const float* b2b  = (const float*)d_in[11];
    const float* b3w  = (const float*)d_in[12];
    const float* b3b  = (const float*)d_in[13];
    const float* wow  = (const float*)d_in[14];
    const int*   center = (const int*)d_in[15];

    const int E = in_sizes[15];
    const int N = in_sizes[0] / H;
    const int nblk = (E + BM - 1) / BM;

    float* pre      = (float*)d_ws;                       // N*H
    float* logits   = pre + (size_t)N*H;                  // E*4
    float* mbuf     = logits + (size_t)E*NHEADS;          // N*4
    float* dbuf     = mbuf + (size_t)N*NHEADS;            // N*4
    int*   start    = (int*)(dbuf + (size_t)N*NHEADS);    // N+1 (padded)
    float* nodebias = (float*)(start + ((N+1+3)&~3));     // N*H
    short* wf1b     = (short*)(nodebias + (size_t)N*H);   // 512*256
    short* wf2b     = wf1b + 512*256;                     // 256*256
    short* w3fb     = wf2b + 256*256;                     // 16*256
    short* wf1v     = w3fb + 16*256;                      // 512*256
    short* wf2v     = wf1v + 512*256;                     // 256*256
    short* wf3v     = wf2v + 256*256;                     // 256*256

    hipMemsetAsync(pre, 0, (size_t)N*H*sizeof(float), stream);
    k_ranges<<<(N+1+255)/256, 256, 0, stream>>>(center, start, E, N);
    k_wconvf<<<dim3(16,8), 256, 0, stream>>>(b1w + 256*H, wf1b, 512);
    k_wconvf<<<dim3(16,4), 256, 0, stream>>>(b2w,  wf2b, 256);
    k_w3padf<<<1, 256, 0, stream>>>(b3w, w3fb);
    k_wconvf<<<dim3(16,8), 256, 0, stream>>>(wv1w, wf1v, 512);
    k_wconvf<<<dim3(16,4), 256, 0, stream>>>(wv2w, wf2v, 256);
    k_wconvf<<<dim3(16,4), 256, 0, stream>>>(wv3w, wf3v, 256);
    k_nodebias<<<N/8, 256, 0, stream>>>(hV, b1w, b1b, nodebias, N);
    k_bias2<<<nblk, 256, 0, stream>>>(hE, wf1b, wf2b, w3fb, b3b, b2b, nodebias, center, logits, E);
    k_smstats<<<N, 64, 0, stream>>>(logits, start, mbuf, dbuf);
    k_wv2<<<nblk, 256, 0, stream>>>(hE, wf1v, wv1b, wf2v, wv2b, wf3v, wv3b,
                                    center, logits, mbuf, dbuf, pre, E);
    k_out<<<N/8, 256, 0, stream>>>(pre, wow, (float*)d_out, N);
}